// Round 3
// baseline (493.027 us; speedup 1.0000x reference)
//
#include <hip/hip_runtime.h>
#include <math.h>

#define G 8
#define Hd 256
#define Wd 256
#define HW (Hd * Wd)

typedef float fvec4 __attribute__((ext_vector_type(4)));

// ---------------------------------------------------------------------------
// v4: back to v2 shape (512 blocks x 1024 thr = 2 blocks/CU, 8 waves/SIMD --
// v3 showed this kernel is latency-bound below that), with the GLCM inner
// loop restructured around a position-packed layout:
//
//   lane L covers columns 4L..4L+3 via ONE global_load_dwordx4 per row.
//   Bit b of position-k mask <-> column 4b+k. Consequences:
//     - 1 vector load per row (was 4 scalar loads + 4 address chains)
//     - column+-1 shifted j-masks are register RENAMES for 3 of 4 positions:
//         mjl_k = MJ[k-1] (k>=1),  mjr_k = MJ[k+1] (k<=2)
//       only mjl_0 = (MJ[3]<<1)|pad and mjr_3 = (MJ[0]>>1)|pad are real shifts.
//   b2 bitplane via ballot(r >= 4.0f), r = v*7: identical to ((int)r & 4)
//   for r in [0,8). Full unroll of the 15-row loop (compile-time prefetch
//   guards); __launch_bounds__(1024,8) pins VGPR<=64 so 2 blocks/CU holds.
//
// GLCM math otherwise identical to the verified v2 kernel:
//   lane L owns bin L (i = L>>3, j = L&7); Mi is a lane permutation of MJ
//   (mi[L] = MJ[L>>3], ds_bpermute pair) consumed one row later; cnt0
//   (angle 0, same-row left neighbor) deferred one row through MJp/mjl0p.
// Pair semantics (d=1, angles 0, pi/4, pi/2, 3pi/4), zero-padded borders;
// OOB neighbor -> q=0 -> bin j=0 (JL0/JR0 pad bits, MJPAD pad row).
// Scale pass fused into the tail (re-read is L3-resident; NT stores).
// ---------------------------------------------------------------------------
__global__ __launch_bounds__(1024, 8) void glcm_fused(const float* __restrict__ x,
                                                      const float* __restrict__ W1,
                                                      const float* __restrict__ W2,
                                                      float* __restrict__ out) {
    __shared__ unsigned int hist[4 * 64];   // [angle][i*8+j]
    __shared__ float feats_s[16];
    __shared__ float h_s[16];
    __shared__ float wplus_s;

    const int t = threadIdx.x;
    const int bc = blockIdx.x;              // b*64 + c
    const float* img = x + (size_t)bc * HW;
    const fvec4* img4 = (const fvec4*)img;  // row y = img4[y*64 + lane]

    if (t < 256) hist[t] = 0u;

    const int lane = t & 63;
    const int wv = t >> 6;                  // 0..15
    const int r0 = wv << 4;                 // first owned row

    // j-selectors (j = lane&7): XNOR-select composition of ballot bitplanes.
    const unsigned long long F0 = (lane & 1) ? 0ull : ~0ull;
    const unsigned long long F1 = (lane & 2) ? 0ull : ~0ull;
    const unsigned long long F2 = (lane & 4) ? 0ull : ~0ull;
    const unsigned long long MJPAD = F0 & F1 & F2;        // mask of a zero-pad row
    const unsigned long long JL0 = MJPAD & 1ull;          // left-edge pad bit
    const unsigned long long JR0 = MJPAD & (1ull << 63);  // right-edge pad bit
    const int baddr = (lane >> 3) << 2;     // ds_bpermute byte addr: lane i(L)

    unsigned int cnt0 = 0, cnt1 = 0, cnt2 = 0, cnt3 = 0;

    unsigned long long MJ[4];               // j-match masks, current row, per pos
    unsigned long long Mi_prev[4];          // i-match masks of previous row
    unsigned long long MJp[3];              // prev row MJ[0..2] (for deferred cnt0)
    unsigned long long mjl0p;               // prev row mjl_0
    fvec4 vn;

    auto bperm64 = [&](unsigned long long v) -> unsigned long long {
        const unsigned int lo =
            (unsigned int)__builtin_amdgcn_ds_bpermute(baddr, (int)(unsigned int)v);
        const unsigned int hi =
            (unsigned int)__builtin_amdgcn_ds_bpermute(baddr, (int)(unsigned int)(v >> 32));
        return ((unsigned long long)hi << 32) | lo;
    };
    auto make_mj = [&](fvec4 v) {
        #pragma unroll
        for (int k = 0; k < 4; ++k) {
            const float r = v[k] * 7.0f;
            const int q = (int)r;
            const unsigned long long b0 = __ballot(q & 1);
            const unsigned long long b1 = __ballot(q & 2);
            const unsigned long long b2 = __ballot(r >= 4.0f);
            MJ[k] = (b0 ^ F0) & (b1 ^ F1) & (b2 ^ F2);
        }
    };

    // ---- prologue: row r0 (its cnt0 is deferred to the next iteration) ----
    {
        const fvec4 vc = img4[r0 * 64 + lane];
        vn = img4[(r0 + 1) * 64 + lane];
        make_mj(vc);
        MJp[0] = MJ[0]; MJp[1] = MJ[1]; MJp[2] = MJ[2];
        mjl0p = (MJ[3] << 1) | JL0;
        #pragma unroll
        for (int k = 0; k < 4; ++k) Mi_prev[k] = bperm64(MJ[k]);
    }

    // ---- rows r0+1 .. r0+15 (fully unrolled; compile-time load guards) ----
    #pragma unroll
    for (int yy = 1; yy < 16; ++yy) {
        const fvec4 cur = vn;
        if (yy < 15) {
            vn = img4[(r0 + yy + 1) * 64 + lane];       // always in-bounds
        } else if (r0 + 16 < Hd) {                      // wave-uniform guard
            vn = img4[(r0 + 16) * 64 + lane];
        }
        make_mj(cur);
        const unsigned long long mjl0 = (MJ[3] << 1) | JL0;
        const unsigned long long mjr3 = (MJ[0] >> 1) | JR0;

        // angle0 of row yy-1 (deferred): same-row left neighbor
        cnt0 += __popcll(Mi_prev[0] & mjl0p) + __popcll(Mi_prev[1] & MJp[0])
              + __popcll(Mi_prev[2] & MJp[1]) + __popcll(Mi_prev[3] & MJp[2]);
        // angle1: down-left     angle2: down      angle3: down-right
        cnt1 += __popcll(Mi_prev[0] & mjl0)  + __popcll(Mi_prev[1] & MJ[0])
              + __popcll(Mi_prev[2] & MJ[1]) + __popcll(Mi_prev[3] & MJ[2]);
        cnt2 += __popcll(Mi_prev[0] & MJ[0]) + __popcll(Mi_prev[1] & MJ[1])
              + __popcll(Mi_prev[2] & MJ[2]) + __popcll(Mi_prev[3] & MJ[3]);
        cnt3 += __popcll(Mi_prev[0] & MJ[1]) + __popcll(Mi_prev[1] & MJ[2])
              + __popcll(Mi_prev[2] & MJ[3]) + __popcll(Mi_prev[3] & mjr3);

        MJp[0] = MJ[0]; MJp[1] = MJ[1]; MJp[2] = MJ[2];
        mjl0p = mjl0;
        #pragma unroll
        for (int k = 0; k < 4; ++k) Mi_prev[k] = bperm64(MJ[k]);
    }

    // ---- boundary row r0+16 (next wave's first row, or zero pad) ----
    if (r0 + 16 < Hd) {
        make_mj(vn);
    } else {
        #pragma unroll
        for (int k = 0; k < 4; ++k) MJ[k] = MJPAD;
    }
    {
        const unsigned long long mjl0 = (MJ[3] << 1) | JL0;
        const unsigned long long mjr3 = (MJ[0] >> 1) | JR0;
        cnt0 += __popcll(Mi_prev[0] & mjl0p) + __popcll(Mi_prev[1] & MJp[0])
              + __popcll(Mi_prev[2] & MJp[1]) + __popcll(Mi_prev[3] & MJp[2]);
        cnt1 += __popcll(Mi_prev[0] & mjl0)  + __popcll(Mi_prev[1] & MJ[0])
              + __popcll(Mi_prev[2] & MJ[1]) + __popcll(Mi_prev[3] & MJ[2]);
        cnt2 += __popcll(Mi_prev[0] & MJ[0]) + __popcll(Mi_prev[1] & MJ[1])
              + __popcll(Mi_prev[2] & MJ[2]) + __popcll(Mi_prev[3] & MJ[3]);
        cnt3 += __popcll(Mi_prev[0] & MJ[1]) + __popcll(Mi_prev[1] & MJ[2])
              + __popcll(Mi_prev[2] & MJ[3]) + __popcll(Mi_prev[3] & mjr3);
    }

    __syncthreads();                        // hist init visible
    atomicAdd(&hist[  0 + lane], cnt0);
    atomicAdd(&hist[ 64 + lane], cnt1);
    atomicAdd(&hist[128 + lane], cnt2);
    atomicAdd(&hist[192 + lane], cnt3);
    __syncthreads();

    // ---- features: wave a (t<256) handles angle a; 64 bins = 64 lanes ----
    if (t < 256) {
        float csum, hsum, esum, rsum;
        {
            const int a = t >> 6;
            const int bin = t & 63;
            const float p = (float)hist[a * 64 + bin] * (1.0f / 65536.0f);
            const int i = bin >> 3, j = bin & 7;
            const int dij = i - j;
            const int adij = dij < 0 ? -dij : dij;
            csum = (float)(dij * dij) * p;
            hsum = p / (float)(1 + adij);
            esum = p * p;
            rsum = ((float)i - 3.5f) * ((float)j - 3.5f) * p;
        }
        #pragma unroll
        for (int m = 1; m < 64; m <<= 1) {
            csum += __shfl_xor(csum, m, 64);
            hsum += __shfl_xor(hsum, m, 64);
            esum += __shfl_xor(esum, m, 64);
            rsum += __shfl_xor(rsum, m, 64);
        }
        if ((t & 63) == 0) {
            const int a = t >> 6;
            feats_s[a * 4 + 0] = csum;
            feats_s[a * 4 + 1] = hsum;
            feats_s[a * 4 + 2] = esum;
            // I_STD^2 + 1e-6, I_STD = sqrt(6) (ddof=1 std of arange(8))
            feats_s[a * 4 + 3] = rsum * (1.0f / 6.000001f);
        }
    }
    __syncthreads();

    // ---- MLP: h = relu(feats @ W1); z = h @ W2[:, c]; w = sigmoid(z) ----
    if (t < 16) {
        float acc = 0.0f;
        #pragma unroll
        for (int f = 0; f < 16; ++f) acc += feats_s[f] * W1[f * 16 + t];
        h_s[t] = acc > 0.0f ? acc : 0.0f;
    }
    __syncthreads();
    if (t == 0) {
        const int c = bc & 63;
        float z = 0.0f;
        #pragma unroll
        for (int k = 0; k < 16; ++k) z += h_s[k] * W2[k * 64 + c];
        const float w = 1.0f / (1.0f + expf(-z));
        wplus_s = w + 1.0f;
    }
    __syncthreads();

    // ---- fused scale: out = x * wplus. Image re-read is L3-resident. ----
    const float w = wplus_s;
    fvec4* out4 = (fvec4*)(out + (size_t)bc * HW);
    #pragma unroll
    for (int k = 0; k < 16; ++k) {
        fvec4 p = img4[k * 1024 + t];
        p *= w;
        __builtin_nontemporal_store(p, &out4[k * 1024 + t]);
    }
}

extern "C" void kernel_launch(void* const* d_in, const int* in_sizes, int n_in,
                              void* d_out, int out_size, void* d_ws, size_t ws_size,
                              hipStream_t stream) {
    (void)in_sizes; (void)n_in; (void)d_ws; (void)ws_size; (void)out_size;
    const float* x  = (const float*)d_in[0];
    const float* W1 = (const float*)d_in[1];   // (16,16) row-major
    const float* W2 = (const float*)d_in[2];   // (16,64) row-major
    float* out = (float*)d_out;

    glcm_fused<<<512, 1024, 0, stream>>>(x, W1, W2, out);
}

// Round 4
// 248.904 us; speedup vs baseline: 1.9808x; 1.9808x over previous
//
#include <hip/hip_runtime.h>
#include <math.h>

#define G 8
#define Hd 256
#define Wd 256
#define HW (Hd * Wd)

typedef float fvec4 __attribute__((ext_vector_type(4)));

// ---------------------------------------------------------------------------
// v5 = v2's exact resource shape (512 blocks x 1024 thr, plain launch_bounds,
// dynamic row loop, depth-1 SW pipeline -- the config measured at 93.5 us)
// with v4's position-packed inner loop (verified bit-exact in v4's run):
//
//   lane L covers columns 4L..4L+3 via ONE global_load_dwordx4 per row.
//   Bit b of position-k mask <-> column 4b+k. Consequences:
//     - 1 vector load per row (was 4 scalar loads + 4 address chains)
//     - column+-1 shifted j-masks are register RENAMES for 3 of 4 positions:
//         mjl_k = MJ[k-1] (k>=1),  mjr_k = MJ[k+1] (k<=2)
//       only mjl_0 = (MJ[3]<<1)|pad and mjr_3 = (MJ[0]>>1)|pad are real shifts.
//   b2 bitplane via ballot(r >= 4.0f), r = v*7 (== ((int)r & 4) for r in [0,8)).
//
// v4's 343 us regression was launch_bounds(1024,8) register-clamp + full
// unroll => scratch spill (FETCH 426 MB / WRITE 713 MB). Both reverted here.
//
// GLCM math identical to verified kernels:
//   lane L owns bin L (i = L>>3, j = L&7); Mi is a lane permutation of MJ
//   (mi[L] = MJ[L>>3], ds_bpermute pair) consumed one row later; cnt0
//   (angle 0, same-row left neighbor) deferred one row through MJp/mjl0p.
// Pair semantics (d=1, angles 0, pi/4, pi/2, 3pi/4), zero-padded borders;
// OOB neighbor -> q=0 -> bin j=0 (JL0/JR0 pad bits, MJPAD pad row).
// Scale pass fused into the tail (re-read is L3-resident; NT stores).
// ---------------------------------------------------------------------------
__global__ __launch_bounds__(1024) void glcm_fused(const float* __restrict__ x,
                                                   const float* __restrict__ W1,
                                                   const float* __restrict__ W2,
                                                   float* __restrict__ out) {
    __shared__ unsigned int hist[4 * 64];   // [angle][i*8+j]
    __shared__ float feats_s[16];
    __shared__ float h_s[16];
    __shared__ float wplus_s;

    const int t = threadIdx.x;
    const int bc = blockIdx.x;              // b*64 + c
    const float* img = x + (size_t)bc * HW;
    const fvec4* img4 = (const fvec4*)img;  // row y = img4[y*64 + lane]

    if (t < 256) hist[t] = 0u;

    const int lane = t & 63;
    const int wv = t >> 6;                  // 0..15
    const int r0 = wv << 4;                 // first owned row

    // j-selectors (j = lane&7): XNOR-select composition of ballot bitplanes.
    const unsigned long long F0 = (lane & 1) ? 0ull : ~0ull;
    const unsigned long long F1 = (lane & 2) ? 0ull : ~0ull;
    const unsigned long long F2 = (lane & 4) ? 0ull : ~0ull;
    const unsigned long long MJPAD = F0 & F1 & F2;        // mask of a zero-pad row
    const unsigned long long JL0 = MJPAD & 1ull;          // left-edge pad bit
    const unsigned long long JR0 = MJPAD & (1ull << 63);  // right-edge pad bit
    const int baddr = (lane >> 3) << 2;     // ds_bpermute byte addr: lane i(L)

    unsigned int cnt0 = 0, cnt1 = 0, cnt2 = 0, cnt3 = 0;

    unsigned long long MJ[4];               // j-match masks, current row, per pos
    unsigned long long Mi_prev[4];          // i-match masks of previous row
    unsigned long long MJp[3];              // prev row MJ[0..2] (for deferred cnt0)
    unsigned long long mjl0p;               // prev row mjl_0
    fvec4 vn;

    auto bperm64 = [&](unsigned long long v) -> unsigned long long {
        const unsigned int lo =
            (unsigned int)__builtin_amdgcn_ds_bpermute(baddr, (int)(unsigned int)v);
        const unsigned int hi =
            (unsigned int)__builtin_amdgcn_ds_bpermute(baddr, (int)(unsigned int)(v >> 32));
        return ((unsigned long long)hi << 32) | lo;
    };
    auto make_mj = [&](fvec4 v) {
        #pragma unroll
        for (int k = 0; k < 4; ++k) {
            const float r = v[k] * 7.0f;
            const int q = (int)r;
            const unsigned long long b0 = __ballot(q & 1);
            const unsigned long long b1 = __ballot(q & 2);
            const unsigned long long b2 = __ballot(r >= 4.0f);
            MJ[k] = (b0 ^ F0) & (b1 ^ F1) & (b2 ^ F2);
        }
    };

    // ---- prologue: row r0 (its cnt0 is deferred to the next iteration) ----
    {
        const fvec4 vc = img4[r0 * 64 + lane];
        vn = img4[(r0 + 1) * 64 + lane];
        make_mj(vc);
        MJp[0] = MJ[0]; MJp[1] = MJ[1]; MJp[2] = MJ[2];
        mjl0p = (MJ[3] << 1) | JL0;
        #pragma unroll
        for (int k = 0; k < 4; ++k) Mi_prev[k] = bperm64(MJ[k]);
    }

    // ---- rows r0+1 .. r0+15 (dynamic loop; depth-1 SW pipeline) ----
    for (int yy = 1; yy < 16; ++yy) {
        const fvec4 cur = vn;
        const int yn = r0 + yy + 1;
        if (yn < Hd) {                      // wave-uniform guard (last wave, yy==15)
            vn = img4[yn * 64 + lane];
        }
        make_mj(cur);
        const unsigned long long mjl0 = (MJ[3] << 1) | JL0;
        const unsigned long long mjr3 = (MJ[0] >> 1) | JR0;

        // angle0 of row yy-1 (deferred): same-row left neighbor
        cnt0 += __popcll(Mi_prev[0] & mjl0p) + __popcll(Mi_prev[1] & MJp[0])
              + __popcll(Mi_prev[2] & MJp[1]) + __popcll(Mi_prev[3] & MJp[2]);
        // angle1: down-left     angle2: down      angle3: down-right
        cnt1 += __popcll(Mi_prev[0] & mjl0)  + __popcll(Mi_prev[1] & MJ[0])
              + __popcll(Mi_prev[2] & MJ[1]) + __popcll(Mi_prev[3] & MJ[2]);
        cnt2 += __popcll(Mi_prev[0] & MJ[0]) + __popcll(Mi_prev[1] & MJ[1])
              + __popcll(Mi_prev[2] & MJ[2]) + __popcll(Mi_prev[3] & MJ[3]);
        cnt3 += __popcll(Mi_prev[0] & MJ[1]) + __popcll(Mi_prev[1] & MJ[2])
              + __popcll(Mi_prev[2] & MJ[3]) + __popcll(Mi_prev[3] & mjr3);

        MJp[0] = MJ[0]; MJp[1] = MJ[1]; MJp[2] = MJ[2];
        mjl0p = mjl0;
        #pragma unroll
        for (int k = 0; k < 4; ++k) Mi_prev[k] = bperm64(MJ[k]);
    }

    // ---- boundary row r0+16 (next wave's first row, or zero pad) ----
    if (r0 + 16 < Hd) {
        make_mj(vn);
    } else {
        #pragma unroll
        for (int k = 0; k < 4; ++k) MJ[k] = MJPAD;
    }
    {
        const unsigned long long mjl0 = (MJ[3] << 1) | JL0;
        const unsigned long long mjr3 = (MJ[0] >> 1) | JR0;
        cnt0 += __popcll(Mi_prev[0] & mjl0p) + __popcll(Mi_prev[1] & MJp[0])
              + __popcll(Mi_prev[2] & MJp[1]) + __popcll(Mi_prev[3] & MJp[2]);
        cnt1 += __popcll(Mi_prev[0] & mjl0)  + __popcll(Mi_prev[1] & MJ[0])
              + __popcll(Mi_prev[2] & MJ[1]) + __popcll(Mi_prev[3] & MJ[2]);
        cnt2 += __popcll(Mi_prev[0] & MJ[0]) + __popcll(Mi_prev[1] & MJ[1])
              + __popcll(Mi_prev[2] & MJ[2]) + __popcll(Mi_prev[3] & MJ[3]);
        cnt3 += __popcll(Mi_prev[0] & MJ[1]) + __popcll(Mi_prev[1] & MJ[2])
              + __popcll(Mi_prev[2] & MJ[3]) + __popcll(Mi_prev[3] & mjr3);
    }

    __syncthreads();                        // hist init visible
    atomicAdd(&hist[  0 + lane], cnt0);
    atomicAdd(&hist[ 64 + lane], cnt1);
    atomicAdd(&hist[128 + lane], cnt2);
    atomicAdd(&hist[192 + lane], cnt3);
    __syncthreads();

    // ---- features: wave a (t<256) handles angle a; 64 bins = 64 lanes ----
    if (t < 256) {
        float csum, hsum, esum, rsum;
        {
            const int a = t >> 6;
            const int bin = t & 63;
            const float p = (float)hist[a * 64 + bin] * (1.0f / 65536.0f);
            const int i = bin >> 3, j = bin & 7;
            const int dij = i - j;
            const int adij = dij < 0 ? -dij : dij;
            csum = (float)(dij * dij) * p;
            hsum = p / (float)(1 + adij);
            esum = p * p;
            rsum = ((float)i - 3.5f) * ((float)j - 3.5f) * p;
        }
        #pragma unroll
        for (int m = 1; m < 64; m <<= 1) {
            csum += __shfl_xor(csum, m, 64);
            hsum += __shfl_xor(hsum, m, 64);
            esum += __shfl_xor(esum, m, 64);
            rsum += __shfl_xor(rsum, m, 64);
        }
        if ((t & 63) == 0) {
            const int a = t >> 6;
            feats_s[a * 4 + 0] = csum;
            feats_s[a * 4 + 1] = hsum;
            feats_s[a * 4 + 2] = esum;
            // I_STD^2 + 1e-6, I_STD = sqrt(6) (ddof=1 std of arange(8))
            feats_s[a * 4 + 3] = rsum * (1.0f / 6.000001f);
        }
    }
    __syncthreads();

    // ---- MLP: h = relu(feats @ W1); z = h @ W2[:, c]; w = sigmoid(z) ----
    if (t < 16) {
        float acc = 0.0f;
        #pragma unroll
        for (int f = 0; f < 16; ++f) acc += feats_s[f] * W1[f * 16 + t];
        h_s[t] = acc > 0.0f ? acc : 0.0f;
    }
    __syncthreads();
    if (t == 0) {
        const int c = bc & 63;
        float z = 0.0f;
        #pragma unroll
        for (int k = 0; k < 16; ++k) z += h_s[k] * W2[k * 64 + c];
        const float w = 1.0f / (1.0f + expf(-z));
        wplus_s = w + 1.0f;
    }
    __syncthreads();

    // ---- fused scale: out = x * wplus. Image re-read is L3-resident. ----
    const float w = wplus_s;
    fvec4* out4 = (fvec4*)(out + (size_t)bc * HW);
    #pragma unroll
    for (int k = 0; k < 16; ++k) {
        fvec4 p = img4[k * 1024 + t];
        p *= w;
        __builtin_nontemporal_store(p, &out4[k * 1024 + t]);
    }
}

extern "C" void kernel_launch(void* const* d_in, const int* in_sizes, int n_in,
                              void* d_out, int out_size, void* d_ws, size_t ws_size,
                              hipStream_t stream) {
    (void)in_sizes; (void)n_in; (void)d_ws; (void)ws_size; (void)out_size;
    const float* x  = (const float*)d_in[0];
    const float* W1 = (const float*)d_in[1];   // (16,16) row-major
    const float* W2 = (const float*)d_in[2];   // (16,64) row-major
    float* out = (float*)d_out;

    glcm_fused<<<512, 1024, 0, stream>>>(x, W1, W2, out);
}

// Round 5
// 248.054 us; speedup vs baseline: 1.9876x; 1.0034x over previous
//
#include <hip/hip_runtime.h>
#include <math.h>

#define G 8
#define Hd 256
#define Wd 256
#define HW (Hd * Wd)

typedef float fvec4 __attribute__((ext_vector_type(4)));

// ---------------------------------------------------------------------------
// v6 = v5 (position-packed GLCM, 512x1024, 2 blocks/CU -- verified 93 us)
// with the scale tail restructured for load-latency hiding:
//   * 8 of the 16 per-thread scale loads are HOISTED above the histogram
//     barrier. They don't depend on wplus (only the multiply does) and hit
//     L2/L3 (the GLCM loop just streamed these lines). Their latency hides
//     under the block-wide GLCM tail skew + barrier/feature/MLP region.
//   * remaining 8 processed as 2 batches of (4 loads -> 4 mul+NT stores)
//     so >=4 loads are in flight per thread (v5's VGPR=32 budget allowed ~2,
//     serializing the tail on L3 latency).
//   * GLCM inner loop byte-identical to v5.
//
// GLCM core (verified):
//   lane L covers columns 4L..4L+3 via ONE global_load_dwordx4 per row;
//   bit b of position-k mask <-> column 4b+k; shifted j-masks are register
//   renames for 3 of 4 positions (only mjl_0/mjr_3 are real shifts).
//   Lane L owns bin L (i = L>>3, j = L&7); Mi is a lane permutation of MJ
//   (mi[L] = MJ[L>>3], ds_bpermute pair) consumed one row later; cnt0
//   (angle 0, same-row left neighbor) deferred one row through MJp/mjl0p.
// Pair semantics (d=1, angles 0, pi/4, pi/2, 3pi/4), zero-padded borders;
// OOB neighbor -> q=0 -> bin j=0 (JL0/JR0 pad bits, MJPAD pad row).
// ---------------------------------------------------------------------------
__global__ __launch_bounds__(1024) void glcm_fused(const float* __restrict__ x,
                                                   const float* __restrict__ W1,
                                                   const float* __restrict__ W2,
                                                   float* __restrict__ out) {
    __shared__ unsigned int hist[4 * 64];   // [angle][i*8+j]
    __shared__ float feats_s[16];
    __shared__ float h_s[16];
    __shared__ float wplus_s;

    const int t = threadIdx.x;
    const int bc = blockIdx.x;              // b*64 + c
    const float* img = x + (size_t)bc * HW;
    const fvec4* img4 = (const fvec4*)img;  // row y = img4[y*64 + lane]

    if (t < 256) hist[t] = 0u;

    const int lane = t & 63;
    const int wv = t >> 6;                  // 0..15
    const int r0 = wv << 4;                 // first owned row

    // j-selectors (j = lane&7): XNOR-select composition of ballot bitplanes.
    const unsigned long long F0 = (lane & 1) ? 0ull : ~0ull;
    const unsigned long long F1 = (lane & 2) ? 0ull : ~0ull;
    const unsigned long long F2 = (lane & 4) ? 0ull : ~0ull;
    const unsigned long long MJPAD = F0 & F1 & F2;        // mask of a zero-pad row
    const unsigned long long JL0 = MJPAD & 1ull;          // left-edge pad bit
    const unsigned long long JR0 = MJPAD & (1ull << 63);  // right-edge pad bit
    const int baddr = (lane >> 3) << 2;     // ds_bpermute byte addr: lane i(L)

    unsigned int cnt0 = 0, cnt1 = 0, cnt2 = 0, cnt3 = 0;

    unsigned long long MJ[4];               // j-match masks, current row, per pos
    unsigned long long Mi_prev[4];          // i-match masks of previous row
    unsigned long long MJp[3];              // prev row MJ[0..2] (for deferred cnt0)
    unsigned long long mjl0p;               // prev row mjl_0
    fvec4 vn;

    auto bperm64 = [&](unsigned long long v) -> unsigned long long {
        const unsigned int lo =
            (unsigned int)__builtin_amdgcn_ds_bpermute(baddr, (int)(unsigned int)v);
        const unsigned int hi =
            (unsigned int)__builtin_amdgcn_ds_bpermute(baddr, (int)(unsigned int)(v >> 32));
        return ((unsigned long long)hi << 32) | lo;
    };
    auto make_mj = [&](fvec4 v) {
        #pragma unroll
        for (int k = 0; k < 4; ++k) {
            const float r = v[k] * 7.0f;
            const int q = (int)r;
            const unsigned long long b0 = __ballot(q & 1);
            const unsigned long long b1 = __ballot(q & 2);
            const unsigned long long b2 = __ballot(r >= 4.0f);
            MJ[k] = (b0 ^ F0) & (b1 ^ F1) & (b2 ^ F2);
        }
    };

    // ---- prologue: row r0 (its cnt0 is deferred to the next iteration) ----
    {
        const fvec4 vc = img4[r0 * 64 + lane];
        vn = img4[(r0 + 1) * 64 + lane];
        make_mj(vc);
        MJp[0] = MJ[0]; MJp[1] = MJ[1]; MJp[2] = MJ[2];
        mjl0p = (MJ[3] << 1) | JL0;
        #pragma unroll
        for (int k = 0; k < 4; ++k) Mi_prev[k] = bperm64(MJ[k]);
    }

    // ---- rows r0+1 .. r0+15 (dynamic loop; depth-1 SW pipeline) ----
    for (int yy = 1; yy < 16; ++yy) {
        const fvec4 cur = vn;
        const int yn = r0 + yy + 1;
        if (yn < Hd) {                      // wave-uniform guard (last wave, yy==15)
            vn = img4[yn * 64 + lane];
        }
        make_mj(cur);
        const unsigned long long mjl0 = (MJ[3] << 1) | JL0;
        const unsigned long long mjr3 = (MJ[0] >> 1) | JR0;

        // angle0 of row yy-1 (deferred): same-row left neighbor
        cnt0 += __popcll(Mi_prev[0] & mjl0p) + __popcll(Mi_prev[1] & MJp[0])
              + __popcll(Mi_prev[2] & MJp[1]) + __popcll(Mi_prev[3] & MJp[2]);
        // angle1: down-left     angle2: down      angle3: down-right
        cnt1 += __popcll(Mi_prev[0] & mjl0)  + __popcll(Mi_prev[1] & MJ[0])
              + __popcll(Mi_prev[2] & MJ[1]) + __popcll(Mi_prev[3] & MJ[2]);
        cnt2 += __popcll(Mi_prev[0] & MJ[0]) + __popcll(Mi_prev[1] & MJ[1])
              + __popcll(Mi_prev[2] & MJ[2]) + __popcll(Mi_prev[3] & MJ[3]);
        cnt3 += __popcll(Mi_prev[0] & MJ[1]) + __popcll(Mi_prev[1] & MJ[2])
              + __popcll(Mi_prev[2] & MJ[3]) + __popcll(Mi_prev[3] & mjr3);

        MJp[0] = MJ[0]; MJp[1] = MJ[1]; MJp[2] = MJ[2];
        mjl0p = mjl0;
        #pragma unroll
        for (int k = 0; k < 4; ++k) Mi_prev[k] = bperm64(MJ[k]);
    }

    // ---- early scale loads (k=0..7): lines just streamed by the GLCM loop,
    //      so L2/L3 hits. Only the loads are hoisted (multiply needs w).
    //      Latency completes during the barrier/feature/MLP sync region. ----
    fvec4 e0 = img4[0 * 1024 + t];
    fvec4 e1 = img4[1 * 1024 + t];
    fvec4 e2 = img4[2 * 1024 + t];
    fvec4 e3 = img4[3 * 1024 + t];
    fvec4 e4 = img4[4 * 1024 + t];
    fvec4 e5 = img4[5 * 1024 + t];
    fvec4 e6 = img4[6 * 1024 + t];
    fvec4 e7 = img4[7 * 1024 + t];

    // ---- boundary row r0+16 (next wave's first row, or zero pad) ----
    if (r0 + 16 < Hd) {
        make_mj(vn);
    } else {
        #pragma unroll
        for (int k = 0; k < 4; ++k) MJ[k] = MJPAD;
    }
    {
        const unsigned long long mjl0 = (MJ[3] << 1) | JL0;
        const unsigned long long mjr3 = (MJ[0] >> 1) | JR0;
        cnt0 += __popcll(Mi_prev[0] & mjl0p) + __popcll(Mi_prev[1] & MJp[0])
              + __popcll(Mi_prev[2] & MJp[1]) + __popcll(Mi_prev[3] & MJp[2]);
        cnt1 += __popcll(Mi_prev[0] & mjl0)  + __popcll(Mi_prev[1] & MJ[0])
              + __popcll(Mi_prev[2] & MJ[1]) + __popcll(Mi_prev[3] & MJ[2]);
        cnt2 += __popcll(Mi_prev[0] & MJ[0]) + __popcll(Mi_prev[1] & MJ[1])
              + __popcll(Mi_prev[2] & MJ[2]) + __popcll(Mi_prev[3] & MJ[3]);
        cnt3 += __popcll(Mi_prev[0] & MJ[1]) + __popcll(Mi_prev[1] & MJ[2])
              + __popcll(Mi_prev[2] & MJ[3]) + __popcll(Mi_prev[3] & mjr3);
    }

    __syncthreads();                        // hist init visible
    atomicAdd(&hist[  0 + lane], cnt0);
    atomicAdd(&hist[ 64 + lane], cnt1);
    atomicAdd(&hist[128 + lane], cnt2);
    atomicAdd(&hist[192 + lane], cnt3);
    __syncthreads();

    // ---- features: wave a (t<256) handles angle a; 64 bins = 64 lanes ----
    if (t < 256) {
        float csum, hsum, esum, rsum;
        {
            const int a = t >> 6;
            const int bin = t & 63;
            const float p = (float)hist[a * 64 + bin] * (1.0f / 65536.0f);
            const int i = bin >> 3, j = bin & 7;
            const int dij = i - j;
            const int adij = dij < 0 ? -dij : dij;
            csum = (float)(dij * dij) * p;
            hsum = p / (float)(1 + adij);
            esum = p * p;
            rsum = ((float)i - 3.5f) * ((float)j - 3.5f) * p;
        }
        #pragma unroll
        for (int m = 1; m < 64; m <<= 1) {
            csum += __shfl_xor(csum, m, 64);
            hsum += __shfl_xor(hsum, m, 64);
            esum += __shfl_xor(esum, m, 64);
            rsum += __shfl_xor(rsum, m, 64);
        }
        if ((t & 63) == 0) {
            const int a = t >> 6;
            feats_s[a * 4 + 0] = csum;
            feats_s[a * 4 + 1] = hsum;
            feats_s[a * 4 + 2] = esum;
            // I_STD^2 + 1e-6, I_STD = sqrt(6) (ddof=1 std of arange(8))
            feats_s[a * 4 + 3] = rsum * (1.0f / 6.000001f);
        }
    }
    __syncthreads();

    // ---- MLP: h = relu(feats @ W1); z = h @ W2[:, c]; w = sigmoid(z) ----
    if (t < 16) {
        float acc = 0.0f;
        #pragma unroll
        for (int f = 0; f < 16; ++f) acc += feats_s[f] * W1[f * 16 + t];
        h_s[t] = acc > 0.0f ? acc : 0.0f;
    }
    __syncthreads();
    if (t == 0) {
        const int c = bc & 63;
        float z = 0.0f;
        #pragma unroll
        for (int k = 0; k < 16; ++k) z += h_s[k] * W2[k * 64 + c];
        const float w = 1.0f / (1.0f + expf(-z));
        wplus_s = w + 1.0f;
    }
    __syncthreads();

    // ---- fused scale: held half is mul+store only; second half batched 4-deep ----
    const float w = wplus_s;
    fvec4* out4 = (fvec4*)(out + (size_t)bc * HW);

    e0 *= w; e1 *= w; e2 *= w; e3 *= w;
    e4 *= w; e5 *= w; e6 *= w; e7 *= w;
    __builtin_nontemporal_store(e0, &out4[0 * 1024 + t]);
    __builtin_nontemporal_store(e1, &out4[1 * 1024 + t]);
    __builtin_nontemporal_store(e2, &out4[2 * 1024 + t]);
    __builtin_nontemporal_store(e3, &out4[3 * 1024 + t]);
    __builtin_nontemporal_store(e4, &out4[4 * 1024 + t]);
    __builtin_nontemporal_store(e5, &out4[5 * 1024 + t]);
    __builtin_nontemporal_store(e6, &out4[6 * 1024 + t]);
    __builtin_nontemporal_store(e7, &out4[7 * 1024 + t]);

    #pragma unroll
    for (int k = 8; k < 16; k += 4) {
        fvec4 a = img4[(k + 0) * 1024 + t];
        fvec4 b = img4[(k + 1) * 1024 + t];
        fvec4 c = img4[(k + 2) * 1024 + t];
        fvec4 d = img4[(k + 3) * 1024 + t];
        a *= w; b *= w; c *= w; d *= w;
        __builtin_nontemporal_store(a, &out4[(k + 0) * 1024 + t]);
        __builtin_nontemporal_store(b, &out4[(k + 1) * 1024 + t]);
        __builtin_nontemporal_store(c, &out4[(k + 2) * 1024 + t]);
        __builtin_nontemporal_store(d, &out4[(k + 3) * 1024 + t]);
    }
}

extern "C" void kernel_launch(void* const* d_in, const int* in_sizes, int n_in,
                              void* d_out, int out_size, void* d_ws, size_t ws_size,
                              hipStream_t stream) {
    (void)in_sizes; (void)n_in; (void)d_ws; (void)ws_size; (void)out_size;
    const float* x  = (const float*)d_in[0];
    const float* W1 = (const float*)d_in[1];   // (16,16) row-major
    const float* W2 = (const float*)d_in[2];   // (16,64) row-major
    float* out = (float*)d_out;

    glcm_fused<<<512, 1024, 0, stream>>>(x, W1, W2, out);
}